// Round 18
// baseline (221.124 us; speedup 1.0000x reference)
//
#include <hip/hip_runtime.h>

typedef __attribute__((ext_vector_type(8)))  short  short8;
typedef __attribute__((ext_vector_type(4)))  short  short4v;
typedef __attribute__((ext_vector_type(4)))  float  f32x4;
typedef __attribute__((ext_vector_type(16))) float  f32x16;
typedef __attribute__((ext_vector_type(8)))  __bf16 bf8_t;
typedef __attribute__((ext_vector_type(4)))  __bf16 bf4_t;
typedef __attribute__((ext_vector_type(2)))  __bf16 bf2_t;
typedef __attribute__((ext_vector_type(4)))  unsigned uint4v;

#define DMODEL 1024
#define SEQ    2048
#define NB     4
#define NH     16
#define MTOT   (NB * SEQ)
#define DM2    ((size_t)DMODEL * DMODEL)
// (1/sqrt(64)) * log2(e): folded into Q projection so softmax runs in log2 domain
#define SCALE_LOG2E 0.18033688011112042f
// attn LDS (r17): zero-pad layout, bank spread via 2-term image swizzle
#define CSTRIDE 512
#define TSPAN   (8 * CSTRIDE)  // 4096 shorts per 64-row tile; 4 tiles = 32KB

static __device__ __forceinline__ ushort f2bf(float f) {
  union { float f; unsigned u; } v; v.f = f;
  unsigned r = v.u + 0x7fffu + ((v.u >> 16) & 1u);
  return (ushort)(r >> 16);
}

static __device__ __forceinline__ float fexp2(float x) {
#if __has_builtin(__builtin_amdgcn_exp2f)
  return __builtin_amdgcn_exp2f(x);
#else
  return __expf(x * 0.6931471805599453f);
#endif
}

static __device__ __forceinline__ f32x4 mfma32(short8 a, short8 b, f32x4 c) {
  return __builtin_amdgcn_mfma_f32_16x16x32_bf16(
      __builtin_bit_cast(bf8_t, a), __builtin_bit_cast(bf8_t, b), c, 0, 0, 0);
}

static __device__ __forceinline__ f32x16 mfma3232(short8 a, short8 b, f32x16 c) {
  return __builtin_amdgcn_mfma_f32_32x32x16_bf16(
      __builtin_bit_cast(bf8_t, a), __builtin_bit_cast(bf8_t, b), c, 0, 0, 0);
}

static __device__ __forceinline__ unsigned pk2(float a, float b) {
  bf2_t t; t[0] = (__bf16)a; t[1] = (__bf16)b;
  return __builtin_bit_cast(unsigned, t);
}

// a' = [a_lo | b_lo], b' = [a_hi | b_hi] (swap a's upper half with b's lower)
static __device__ __forceinline__ void plswap(unsigned& a, unsigned& b) {
  asm volatile("v_permlane32_swap_b32 %0, %1" : "+v"(a), "+v"(b));
}

// async global->LDS, 16B per lane; LDS dest wave-uniform base + lane*16
static __device__ __forceinline__ void gl_lds16(const ushort* g, ushort* l) {
  __builtin_amdgcn_global_load_lds(
      (const __attribute__((address_space(1))) unsigned*)(unsigned long long)g,
      (__attribute__((address_space(3))) unsigned*)(unsigned long long)l,
      16, 0, 0);
}

// ---------------- fp32 -> bf16 convert (q,k,v) + mask bias/flags --------------
__global__ __launch_bounds__(256) void cvt3_k(
    const float* __restrict__ q, const float* __restrict__ k,
    const float* __restrict__ v, ushort* __restrict__ qb,
    ushort* __restrict__ kb, ushort* __restrict__ vb,
    const int* __restrict__ mask, float* __restrict__ biasf,
    unsigned* __restrict__ flags) {
  const int z = blockIdx.y;
  if (z == 0 && blockIdx.x < 32) {  // fold mask->bias + per-64-tile flags
    const int t = blockIdx.x * 256 + threadIdx.x;
    const int m = mask[t];
    biasf[t] = m ? 0.f : -1e30f;
    const unsigned long long bal = __ballot(m == 0);
    if ((threadIdx.x & 63) == 0)
      flags[blockIdx.x * 4 + (threadIdx.x >> 6)] = (bal != 0ull) ? 1u : 0u;
  }
  const float* src = (z == 0) ? q : (z == 1) ? k : v;
  ushort* dst = (z == 0) ? qb : (z == 1) ? kb : vb;
  const size_t i = ((size_t)blockIdx.x * 256 + threadIdx.x) * 8;
  const float4 a0 = *(const float4*)&src[i];
  const float4 a1 = *(const float4*)&src[i + 4];
  bf8_t c;
  c[0] = (__bf16)a0.x; c[1] = (__bf16)a0.y; c[2] = (__bf16)a0.z; c[3] = (__bf16)a0.w;
  c[4] = (__bf16)a1.x; c[5] = (__bf16)a1.y; c[6] = (__bf16)a1.z; c[7] = (__bf16)a1.w;
  *(short8*)&dst[i] = __builtin_bit_cast(short8, c);
}

// ---------------- weight transpose: W (K x N) fp32 -> Wt (N x K) bf16 ----------
__global__ __launch_bounds__(1024) void wtrans_k(
    const float* __restrict__ Wq, const float* __restrict__ Wk,
    const float* __restrict__ Wv, const float* __restrict__ Wo,
    ushort* __restrict__ Wt) {
  __shared__ float tile[32][33];
  const int z = blockIdx.z;
  const float* W = (z == 0) ? Wq : (z == 1) ? Wk : (z == 2) ? Wv : Wo;
  ushort* out = Wt + (size_t)z * DM2;
  const int tx = threadIdx.x, ty = threadIdx.y;
  const int n0 = blockIdx.x * 32, k0 = blockIdx.y * 32;
  tile[ty][tx] = W[(size_t)(k0 + ty) * DMODEL + n0 + tx];
  __syncthreads();
  out[(size_t)(n0 + ty) * DMODEL + k0 + tx] = f2bf(tile[tx][ty]);
}

// ---------------- GEMM core: BK=32 DOUBLE-BUFFERED (stage-at-top, 1 barrier) ---
// A rows from M0.., B rows from N0.., both bf16 row-major K=DMODEL.
// Staging chunk = 16 rows x 32 cols (1KB); wave w stages chunks {2w,2w+1} of A
// and B. Source pre-swizzled: lane covers row ch*16+(lane>>2), granule
// (lane&3)^((lane>>2)&3); reads use granule lg^(lr&3): 2 lanes/bank (free).
// Stage of tile ks+1 issued BEFORE compute of tile ks -> full compute phase to
// hide global->LDS latency (attn_k's verified discipline). One barrier/iter.
#define GEMM_BODY(A, Bt, M0v, N0v)                                             \
  __shared__ ushort Asm[2][128 * 32];                                          \
  __shared__ ushort Bsm[2][128 * 32];                                          \
  const int tid = threadIdx.x;                                                 \
  const int wid = tid >> 6, lane = tid & 63;                                   \
  const int wr = wid >> 1, wc = wid & 1;                                       \
  const int lr = lane & 15, lg = lane >> 4;                                    \
  const int m0 = (M0v), n0 = (N0v);                                            \
  const int srow = lane >> 2;                                                  \
  const int sgr = ((lane & 3) ^ (srow & 3)) * 8;                               \
  size_t gA[2], gB[2];                                                         \
  int lco[2];                                                                  \
  _Pragma("unroll") for (int j = 0; j < 2; j++) {                              \
    const int ch = wid * 2 + j;                                                \
    gA[j] = (size_t)(m0 + ch * 16 + srow) * DMODEL + sgr;                      \
    gB[j] = (size_t)(n0 + ch * 16 + srow) * DMODEL + sgr;                      \
    lco[j] = ch * 512;                                                         \
  }                                                                            \
  f32x4 acc[4][4];                                                             \
  _Pragma("unroll") for (int m = 0; m < 4; m++)                                \
      _Pragma("unroll") for (int n = 0; n < 4; n++)                            \
          acc[m][n] = (f32x4){0.f, 0.f, 0.f, 0.f};                             \
  _Pragma("unroll") for (int j = 0; j < 2; j++) {                              \
    gl_lds16(&A[gA[j]], &Asm[0][lco[j]]);                                      \
    gl_lds16(&Bt[gB[j]], &Bsm[0][lco[j]]);                                     \
  }                                                                            \
  __syncthreads();                                                             \
  const int sx = (lg ^ (lr & 3)) * 8;                                          \
  int cur = 0;                                                                 \
  for (int ks = 0; ks < DMODEL / 32; ++ks) {                                   \
    if (ks < DMODEL / 32 - 1) {                                                \
      const size_t ko = (size_t)(ks + 1) * 32;                                 \
      _Pragma("unroll") for (int j = 0; j < 2; j++) {                          \
        gl_lds16(&A[gA[j] + ko], &Asm[cur ^ 1][lco[j]]);                       \
        gl_lds16(&Bt[gB[j] + ko], &Bsm[cur ^ 1][lco[j]]);                      \
      }                                                                        \
    }                                                                          \
    const ushort* As = Asm[cur];                                               \
    const ushort* Bs = Bsm[cur];                                               \
    short8 af[4], bfr[4];                                                      \
    _Pragma("unroll") for (int m = 0; m < 4; m++) af[m] =                      \
        *(const short8*)&As[(wr * 64 + m * 16 + lr) * 32 + sx];                \
    _Pragma("unroll") for (int n = 0; n < 4; n++) bfr[n] =                     \
        *(const short8*)&Bs[(wc * 64 + n * 16 + lr) * 32 + sx];                \
    _Pragma("unroll") for (int m = 0; m < 4; m++)                              \
        _Pragma("unroll") for (int n = 0; n < 4; n++)                          \
            acc[m][n] = mfma32(af[m], bfr[n], acc[m][n]);                      \
    __syncthreads();                                                           \
    cur ^= 1;                                                                  \
  }

// Fused QKV projections (r16 orientation: Q/K swapped-operand epilogues).
// Image swizzle (K and V): col ^ ((row&7)*8) ^ (((row>>3)&3)*16).
__global__ __launch_bounds__(256) void gemmqkv_k(
    const ushort* __restrict__ qb, const ushort* __restrict__ kb,
    const ushort* __restrict__ vb, const ushort* __restrict__ Wt,
    const float* __restrict__ bq, const float* __restrict__ bk,
    const float* __restrict__ bv, ushort* __restrict__ Qp,
    ushort* __restrict__ Kp, ushort* __restrict__ Vb) {
  const int z = blockIdx.z;
  const int bx = blockIdx.x, by = blockIdx.y;
  const ushort* A  = (z == 0) ? Wt : (z == 1) ? (Wt + DM2) : vb;
  const ushort* Bm = (z == 0) ? qb : (z == 1) ? kb : (Wt + 2 * DM2);
  const int M0 = (z == 2) ? bx * 128 : by * 128;
  const int N0 = (z == 2) ? by * 128 : bx * 128;
  GEMM_BODY(A, Bm, M0, N0)

  if (z == 2) {
    // V: row = token (grb+j), col = feature; V image [dk][key ^ swz(dk)]
    float bv4[4];
#pragma unroll
    for (int n = 0; n < 4; n++) bv4[n] = bv[n0 + wc * 64 + n * 16 + lr];
#pragma unroll
    for (int m = 0; m < 4; m++) {
      const int grb = m0 + wr * 64 + m * 16 + lg * 4;
#pragma unroll
      for (int n = 0; n < 4; n++) {
        const int gc = n0 + wc * 64 + n * 16 + lr;
        const int hh = gc >> 6, dk = gc & 63;
        const int bb = grb >> 11, ss = grb & 2047;
        bf4_t pk;
#pragma unroll
        for (int j = 0; j < 4; j++) pk[j] = (__bf16)(acc[m][n][j] + bv4[n]);
        const int swz = ((dk & 7) * 8) ^ (((dk >> 3) & 3) * 16);
        const size_t addr = (((size_t)bb * NH + hh) * SEQ) * 64 +
                            (size_t)(ss >> 6) * 4096 + dk * 64 +
                            ((ss & 63) ^ swz);
        *(short4v*)&Vb[addr] = __builtin_bit_cast(short4v, pk);
      }
    }
  } else {
    // Q/K swapped: row = feature f (j spans 4 aligned dk), col = token
    const float* bias = (z == 0) ? bq : bk;
    ushort* out = (z == 0) ? Qp : Kp;
    const float scale = (z == 0) ? SCALE_LOG2E : 1.f;
#pragma unroll
    for (int m = 0; m < 4; m++) {
      const int f0 = m0 + wr * 64 + m * 16 + lg * 4;  // aligned 4, one head
      const f32x4 b4 = *(const f32x4*)&bias[f0];
      const int hh = f0 >> 6, dk0 = f0 & 63;
#pragma unroll
      for (int n = 0; n < 4; n++) {
        const int t = n0 + wc * 64 + n * 16 + lr;
        const int b = t >> 11, s = t & 2047;
        bf4_t pk;
#pragma unroll
        for (int j = 0; j < 4; j++)
          pk[j] = (__bf16)((acc[m][n][j] + b4[j]) * scale);
        size_t addr;
        if (z == 0) {
          addr = (((size_t)b * NH + hh) * SEQ + s) * 64 + dk0;
        } else {
          // K image: key*64 + (dk ^ swz(key)); swz mult of 8 keeps 4-runs
          const int swz = ((s & 7) * 8) ^ (((s >> 3) & 3) * 16);
          addr = (((size_t)b * NH + hh) * SEQ) * 64 + (size_t)(s >> 6) * 4096 +
                 (s & 63) * 64 + (dk0 ^ swz);
        }
        *(short4v*)&out[addr] = __builtin_bit_cast(short4v, pk);
      }
    }
  }
}

// Final output GEMM: fp32 row-major epilogue.
__global__ __launch_bounds__(256) void gemmo_k(
    const ushort* __restrict__ Ain, const ushort* __restrict__ Btin,
    const float* __restrict__ bias, float* __restrict__ out) {
  GEMM_BODY(Ain, Btin, blockIdx.x * 128, blockIdx.y * 128)
  float bv4[4];
#pragma unroll
  for (int n = 0; n < 4; n++) bv4[n] = bias[n0 + wc * 64 + n * 16 + lr];
#pragma unroll
  for (int m = 0; m < 4; m++) {
    const int grb = m0 + wr * 64 + m * 16 + lg * 4;
#pragma unroll
    for (int n = 0; n < 4; n++) {
      const int gc = n0 + wc * 64 + n * 16 + lr;
#pragma unroll
      for (int j = 0; j < 4; j++)
        out[(size_t)(grb + j) * DMODEL + gc] = acc[m][n][j] + bv4[n];
    }
  }
}

// ---------------- flash attention, 32x32 MFMA (r17 config, frozen) -------------
__global__ __launch_bounds__(256) void attn_k(
    const ushort* __restrict__ Qp, const ushort* __restrict__ Kp,
    const ushort* __restrict__ Vt, const float* __restrict__ biasf,
    const unsigned* __restrict__ flags, ushort* __restrict__ ctx) {
  __shared__ ushort smem[4 * TSPAN];  // K dbuf | V dbuf = 32768B; reused for O
  const int tid = threadIdx.x, w = tid >> 6, lane = tid & 63;
  const int q = lane & 31, hi = lane >> 5;
  const int n = blockIdx.x;
  const int xcd = n & 7, idx = n >> 3;
  const int bh = ((idx >> 4) << 3) | xcd;  // 16 consecutive q-tiles share an XCD
  const int qt = idx & 15;
  const int b = bh >> 4, h = bh & 15;
  const int q0w = qt * 128 + w * 32;
  const ushort* Qh = Qp + (size_t)bh * SEQ * 64;
  const ushort* Kh = Kp + (size_t)bh * SEQ * 64;
  const ushort* Vh = Vt + (size_t)bh * SEQ * 64;
  const float* biasb = biasf + b * SEQ;
  const unsigned* flb = flags + b * 32;

  // Q fragments (B-operand of QK^T): col=q, k = c*16 + hi*8 + j
  short8 qf[4];
#pragma unroll
  for (int c = 0; c < 4; c++)
    qf[c] = *(const short8*)&Qh[(size_t)(q0w + q) * 64 + c * 16 + hi * 8];

  // loop-invariant LDS read offsets (shorts); row r at r*64, col ^ swz(r)
  const int xo = ((q & 7) * 8) ^ (((q >> 3) & 3) * 16);
  const int rbase = q * 64;
  int off[4];
#pragma unroll
  for (int c = 0; c < 4; c++) off[c] = rbase + ((c * 16 + hi * 8) ^ xo);

  // staging: wave w covers chunks {2w, 2w+1} (8 rows = 1KB each) of K and V
  const int sl = lane * 8;
  const int c0 = 2 * w, c1 = 2 * w + 1;

  f32x16 o0, o1;
#pragma unroll
  for (int r = 0; r < 16; r++) { o0[r] = 0.f; o1[r] = 0.f; }
  float l_run = 0.f;

  // prologue: stage tile 0 into buffer 0 (async, drained by the barrier)
  gl_lds16(&Kh[c0 * 512 + sl], &smem[c0 * CSTRIDE]);
  gl_lds16(&Kh[c1 * 512 + sl], &smem[c1 * CSTRIDE]);
  gl_lds16(&Vh[c0 * 512 + sl], &smem[2 * TSPAN + c0 * CSTRIDE]);
  gl_lds16(&Vh[c1 * 512 + sl], &smem[2 * TSPAN + c1 * CSTRIDE]);
  __syncthreads();

  for (int it = 0; it < 32; ++it) {
    const int cur = it & 1;
    // stage next tile into the buffer freed by the previous barrier
    if (it < 31) {
      const size_t tb = (size_t)(it + 1) * 4096;
      ushort* kd = &smem[(cur ^ 1) * TSPAN];
      ushort* vd = &smem[2 * TSPAN + (cur ^ 1) * TSPAN];
      gl_lds16(&Kh[tb + c0 * 512 + sl], &kd[c0 * CSTRIDE]);
      gl_lds16(&Kh[tb + c1 * 512 + sl], &kd[c1 * CSTRIDE]);
      gl_lds16(&Vh[tb + c0 * 512 + sl], &vd[c0 * CSTRIDE]);
      gl_lds16(&Vh[tb + c1 * 512 + sl], &vd[c1 * CSTRIDE]);
    }

    const ushort* kl = &smem[cur * TSPAN];
    const ushort* vl = &smem[2 * TSPAN + cur * TSPAN];

    f32x16 s0, s1;
#pragma unroll
    for (int r = 0; r < 16; r++) { s0[r] = 0.f; s1[r] = 0.f; }
#pragma unroll
    for (int c = 0; c < 4; c++)
      s0 = mfma3232(*(const short8*)&kl[off[c]], qf[c], s0);
#pragma unroll
    for (int c = 0; c < 4; c++)
      s1 = mfma3232(*(const short8*)&kl[off[c] + 2048], qf[c], s1);

    // softmax numerator (log2 domain, no shift; masked -> exp2(-1e30)=0)
    float p[32];
    if (flb[it]) {  // uniform branch: tile has masked keys
      const float* bp = biasb + it * 64;
#pragma unroll
      for (int kt = 0; kt < 2; kt++)
#pragma unroll
        for (int g = 0; g < 4; g++) {
          const f32x4 ba = *(const f32x4*)&bp[kt * 32 + g * 8 + hi * 4];
#pragma unroll
          for (int j = 0; j < 4; j++)
            p[kt * 16 + g * 4 + j] =
                fexp2((kt ? s1[g * 4 + j] : s0[g * 4 + j]) + ba[j]);
        }
    } else {
#pragma unroll
      for (int r = 0; r < 16; r++) {
        p[r] = fexp2(s0[r]);
        p[16 + r] = fexp2(s1[r]);
      }
    }

    // tree sum (depth 5)
    float a16[16], a8[8], a4[4];
#pragma unroll
    for (int i = 0; i < 16; i++) a16[i] = p[i] + p[16 + i];
#pragma unroll
    for (int i = 0; i < 8; i++) a8[i] = a16[i] + a16[8 + i];
#pragma unroll
    for (int i = 0; i < 4; i++) a4[i] = a8[i] + a8[4 + i];
    float ps = (a4[0] + a4[1]) + (a4[2] + a4[3]);
    ps += __shfl_xor(ps, 32);
    l_run += ps;

    // P -> PV B-operands: per 16-key block kb, pack 4 u32 then one
    // permlane32_swap per pair fills both B words (lane halves exchanged)
    short8 frag[4];
#pragma unroll
    for (int kb = 0; kb < 4; kb++) {
      unsigned X0 = pk2(p[8 * kb + 0], p[8 * kb + 1]);
      unsigned X1 = pk2(p[8 * kb + 2], p[8 * kb + 3]);
      unsigned Y0 = pk2(p[8 * kb + 4], p[8 * kb + 5]);
      unsigned Y1 = pk2(p[8 * kb + 6], p[8 * kb + 7]);
      plswap(X0, Y0);
      plswap(X1, Y1);
      frag[kb] = __builtin_bit_cast(short8, (uint4v){X0, X1, Y0, Y1});
    }

#pragma unroll
    for (int kb = 0; kb < 4; kb++) {
      o0 = mfma3232(*(const short8*)&vl[off[kb]], frag[kb], o0);
      o1 = mfma3232(*(const short8*)&vl[off[kb] + 2048], frag[kb], o1);
    }

    __syncthreads();  // drains staging loads + this tile's LDS reads
  }

  // epilogue: normalize, bf16 transpose O^T -> row-major via LDS, store
  const float inv = 1.f / l_run;
  ushort* ow = &smem[w * 2176];  // [32 q][68] bf16
#pragma unroll
  for (int r = 0; r < 16; r++) {
    const int dk = (r & 3) + 8 * (r >> 2) + 4 * hi;
    ow[q * 68 + dk] = __builtin_bit_cast(ushort, (__bf16)(o0[r] * inv));
    ow[q * 68 + 32 + dk] = __builtin_bit_cast(ushort, (__bf16)(o1[r] * inv));
  }
  __syncthreads();
  const int sr = lane >> 4, dc = (lane & 15) * 4;
#pragma unroll
  for (int i = 0; i < 8; i++) {
    const int qq = i * 4 + sr;
    const short4v vv = *(const short4v*)&ow[qq * 68 + dc];
    *(short4v*)&ctx[((size_t)b * SEQ + q0w + qq) * DMODEL + h * 64 + dc] = vv;
  }
}

// ---------------- host ---------------------------------------------------------
extern "C" void kernel_launch(void* const* d_in, const int* in_sizes, int n_in,
                              void* d_out, int out_size, void* d_ws,
                              size_t ws_size, hipStream_t stream) {
  const float* q    = (const float*)d_in[0];
  const float* k    = (const float*)d_in[1];
  const float* v    = (const float*)d_in[2];
  const int*   mask = (const int*)d_in[3];
  const float* Wq   = (const float*)d_in[4];
  const float* bq   = (const float*)d_in[5];
  const float* Wk   = (const float*)d_in[6];
  const float* bk   = (const float*)d_in[7];
  const float* Wv   = (const float*)d_in[8];
  const float* bv   = (const float*)d_in[9];
  const float* Wo   = (const float*)d_in[10];
  const float* bo   = (const float*)d_in[11];

  char* p = (char*)d_ws;
  ushort* Wt = (ushort*)p; p += (size_t)4 * DM2 * 2;
  ushort* Qp = (ushort*)p; p += (size_t)MTOT * DMODEL * 2;
  ushort* Kp = (ushort*)p; p += (size_t)MTOT * DMODEL * 2;
  ushort* Vb = (ushort*)p; p += (size_t)MTOT * DMODEL * 2;
  ushort* qb = (ushort*)p; p += (size_t)MTOT * DMODEL * 2;
  ushort* kb = (ushort*)p; p += (size_t)MTOT * DMODEL * 2;
  ushort* vb = (ushort*)p; p += (size_t)MTOT * DMODEL * 2;
  float*  biasf = (float*)p; p += (size_t)NB * SEQ * 4;
  unsigned* flags = (unsigned*)p;
  // ctx aliases qb: qb's last read (Q projection) precedes attn on the stream
  ushort* ctx = qb;

  wtrans_k<<<dim3(32, 32, 4), dim3(32, 32), 0, stream>>>(Wq, Wk, Wv, Wo, Wt);
  cvt3_k<<<dim3(MTOT * DMODEL / (256 * 8), 3), 256, 0, stream>>>(
      q, k, v, qb, kb, vb, mask, biasf, flags);

  gemmqkv_k<<<dim3(MTOT / 128, DMODEL / 128, 3), 256, 0, stream>>>(
      qb, kb, vb, Wt, bq, bk, bv, Qp, Kp, Vb);

  attn_k<<<1024, 256, 0, stream>>>(Qp, Kp, Vb, biasf, flags, ctx);

  gemmo_k<<<dim3(MTOT / 128, DMODEL / 128), 256, 0, stream>>>(
      ctx, Wt + (size_t)3 * DM2, bo, (float*)d_out);
}

// Round 19
// 207.705 us; speedup vs baseline: 1.0646x; 1.0646x over previous
//
#include <hip/hip_runtime.h>

typedef __attribute__((ext_vector_type(8)))  short  short8;
typedef __attribute__((ext_vector_type(4)))  short  short4v;
typedef __attribute__((ext_vector_type(4)))  float  f32x4;
typedef __attribute__((ext_vector_type(16))) float  f32x16;
typedef __attribute__((ext_vector_type(8)))  __bf16 bf8_t;
typedef __attribute__((ext_vector_type(4)))  __bf16 bf4_t;
typedef __attribute__((ext_vector_type(2)))  __bf16 bf2_t;
typedef __attribute__((ext_vector_type(4)))  unsigned uint4v;

#define DMODEL 1024
#define SEQ    2048
#define NB     4
#define NH     16
#define MTOT   (NB * SEQ)
#define DM2    ((size_t)DMODEL * DMODEL)
// (1/sqrt(64)) * log2(e): folded into Q projection so softmax runs in log2 domain
#define SCALE_LOG2E 0.18033688011112042f
// attn LDS: zero-pad layout; bank spread via image swizzle
//   col ^ ((row&7)*8) ^ (((row>>3)&3)*16)  -> 2 lanes/bank (free, m136)
#define CSTRIDE 512
#define TSPAN   (8 * CSTRIDE)  // 4096 shorts per 64-row tile; 4 tiles = 32KB

static __device__ __forceinline__ ushort f2bf(float f) {
  union { float f; unsigned u; } v; v.f = f;
  unsigned r = v.u + 0x7fffu + ((v.u >> 16) & 1u);
  return (ushort)(r >> 16);
}

static __device__ __forceinline__ float fexp2(float x) {
#if __has_builtin(__builtin_amdgcn_exp2f)
  return __builtin_amdgcn_exp2f(x);
#else
  return __expf(x * 0.6931471805599453f);
#endif
}

static __device__ __forceinline__ f32x4 mfma32(short8 a, short8 b, f32x4 c) {
  return __builtin_amdgcn_mfma_f32_16x16x32_bf16(
      __builtin_bit_cast(bf8_t, a), __builtin_bit_cast(bf8_t, b), c, 0, 0, 0);
}

static __device__ __forceinline__ f32x16 mfma3232(short8 a, short8 b, f32x16 c) {
  return __builtin_amdgcn_mfma_f32_32x32x16_bf16(
      __builtin_bit_cast(bf8_t, a), __builtin_bit_cast(bf8_t, b), c, 0, 0, 0);
}

static __device__ __forceinline__ unsigned pk2(float a, float b) {
  bf2_t t; t[0] = (__bf16)a; t[1] = (__bf16)b;
  return __builtin_bit_cast(unsigned, t);
}

// a' = [a_lo | b_lo], b' = [a_hi | b_hi] (swap a's upper half with b's lower)
static __device__ __forceinline__ void plswap(unsigned& a, unsigned& b) {
  asm volatile("v_permlane32_swap_b32 %0, %1" : "+v"(a), "+v"(b));
}

// async global->LDS, 16B per lane; LDS dest wave-uniform base + lane*16
static __device__ __forceinline__ void gl_lds16(const ushort* g, ushort* l) {
  __builtin_amdgcn_global_load_lds(
      (const __attribute__((address_space(1))) unsigned*)(unsigned long long)g,
      (__attribute__((address_space(3))) unsigned*)(unsigned long long)l,
      16, 0, 0);
}

// ---------------- fp32 -> bf16 convert (q,k,v) + mask bias/flags --------------
__global__ __launch_bounds__(256) void cvt3_k(
    const float* __restrict__ q, const float* __restrict__ k,
    const float* __restrict__ v, ushort* __restrict__ qb,
    ushort* __restrict__ kb, ushort* __restrict__ vb,
    const int* __restrict__ mask, float* __restrict__ biasf,
    unsigned* __restrict__ flags) {
  const int z = blockIdx.y;
  if (z == 0 && blockIdx.x < 32) {  // fold mask->bias + per-64-tile flags
    const int t = blockIdx.x * 256 + threadIdx.x;
    const int m = mask[t];
    biasf[t] = m ? 0.f : -1e30f;
    const unsigned long long bal = __ballot(m == 0);
    if ((threadIdx.x & 63) == 0)
      flags[blockIdx.x * 4 + (threadIdx.x >> 6)] = (bal != 0ull) ? 1u : 0u;
  }
  const float* src = (z == 0) ? q : (z == 1) ? k : v;
  ushort* dst = (z == 0) ? qb : (z == 1) ? kb : vb;
  const size_t i = ((size_t)blockIdx.x * 256 + threadIdx.x) * 8;
  const float4 a0 = *(const float4*)&src[i];
  const float4 a1 = *(const float4*)&src[i + 4];
  bf8_t c;
  c[0] = (__bf16)a0.x; c[1] = (__bf16)a0.y; c[2] = (__bf16)a0.z; c[3] = (__bf16)a0.w;
  c[4] = (__bf16)a1.x; c[5] = (__bf16)a1.y; c[6] = (__bf16)a1.z; c[7] = (__bf16)a1.w;
  *(short8*)&dst[i] = __builtin_bit_cast(short8, c);
}

// ---------------- weight transpose: W (K x N) fp32 -> Wt (N x K) bf16 ----------
__global__ __launch_bounds__(1024) void wtrans_k(
    const float* __restrict__ Wq, const float* __restrict__ Wk,
    const float* __restrict__ Wv, const float* __restrict__ Wo,
    ushort* __restrict__ Wt) {
  __shared__ float tile[32][33];
  const int z = blockIdx.z;
  const float* W = (z == 0) ? Wq : (z == 1) ? Wk : (z == 2) ? Wv : Wo;
  ushort* out = Wt + (size_t)z * DM2;
  const int tx = threadIdx.x, ty = threadIdx.y;
  const int n0 = blockIdx.x * 32, k0 = blockIdx.y * 32;
  tile[ty][tx] = W[(size_t)(k0 + ty) * DMODEL + n0 + tx];
  __syncthreads();
  out[(size_t)(n0 + ty) * DMODEL + k0 + tx] = f2bf(tile[tx][ty]);
}

// ---------------- GEMM core: BK=64, XOR-swizzled LDS (r13-verified) ------------
#define GEMM_BODY(A, Bt, M0v, N0v)                                              \
  __shared__ ushort Asm[128 * 64];                                              \
  __shared__ ushort Bsm[128 * 64];                                              \
  const int tid = threadIdx.x;                                                  \
  const int wid = tid >> 6, lane = tid & 63;                                    \
  const int wr = wid >> 1, wc = wid & 1;                                        \
  const int lr = lane & 15, lg = lane >> 4;                                     \
  const int m0 = (M0v), n0 = (N0v);                                             \
  const int sr8 = lane >> 3, sg = ((lane & 7) ^ sr8) * 8;                       \
  size_t gA[4], gB[4];                                                          \
  ushort *lA[4], *lB[4];                                                        \
  _Pragma("unroll") for (int j = 0; j < 4; j++) {                               \
    const int ch = wid * 4 + j;                                                 \
    gA[j] = (size_t)(m0 + ch * 8 + sr8) * DMODEL + sg;                          \
    gB[j] = (size_t)(n0 + ch * 8 + sr8) * DMODEL + sg;                          \
    lA[j] = &Asm[ch * 512];                                                     \
    lB[j] = &Bsm[ch * 512];                                                     \
  }                                                                             \
  f32x4 acc[4][4];                                                              \
  _Pragma("unroll") for (int m = 0; m < 4; m++)                                 \
      _Pragma("unroll") for (int n = 0; n < 4; n++)                             \
          acc[m][n] = (f32x4){0.f, 0.f, 0.f, 0.f};                              \
  _Pragma("unroll") for (int j = 0; j < 4; j++) {                               \
    gl_lds16(&A[gA[j]], lA[j]);                                                 \
    gl_lds16(&Bt[gB[j]], lB[j]);                                                \
  }                                                                             \
  const int soff = (lg ^ (lr & 7)) * 8;                                         \
  for (int ks = 0; ks < DMODEL / 64; ++ks) {                                    \
    __syncthreads();                                                            \
    _Pragma("unroll") for (int kk = 0; kk < 2; kk++) {                          \
      const int sx = soff ^ (kk * 32);                                          \
      short8 af[4], bfr[4];                                                     \
      _Pragma("unroll") for (int m = 0; m < 4; m++) af[m] =                     \
          *(const short8*)&Asm[(wr * 64 + m * 16 + lr) * 64 + sx];              \
      _Pragma("unroll") for (int n = 0; n < 4; n++) bfr[n] =                    \
          *(const short8*)&Bsm[(wc * 64 + n * 16 + lr) * 64 + sx];              \
      _Pragma("unroll") for (int m = 0; m < 4; m++)                             \
          _Pragma("unroll") for (int n = 0; n < 4; n++)                         \
              acc[m][n] = mfma32(af[m], bfr[n], acc[m][n]);                     \
    }                                                                           \
    __syncthreads();                                                            \
    if (ks < DMODEL / 64 - 1) {                                                 \
      const size_t ko = (size_t)(ks + 1) * 64;                                  \
      _Pragma("unroll") for (int j = 0; j < 4; j++) {                           \
        gl_lds16(&A[gA[j] + ko], lA[j]);                                        \
        gl_lds16(&Bt[gB[j] + ko], lB[j]);                                       \
      }                                                                         \
    }                                                                           \
  }

// Fused QKV projections (r16 orientation: Q/K swapped-operand epilogues).
// Image swizzle (K and V): col ^ ((row&7)*8) ^ (((row>>3)&3)*16).
__global__ __launch_bounds__(256) void gemmqkv_k(
    const ushort* __restrict__ qb, const ushort* __restrict__ kb,
    const ushort* __restrict__ vb, const ushort* __restrict__ Wt,
    const float* __restrict__ bq, const float* __restrict__ bk,
    const float* __restrict__ bv, ushort* __restrict__ Qp,
    ushort* __restrict__ Kp, ushort* __restrict__ Vb) {
  const int z = blockIdx.z;
  const int bx = blockIdx.x, by = blockIdx.y;
  const ushort* A  = (z == 0) ? Wt : (z == 1) ? (Wt + DM2) : vb;
  const ushort* Bm = (z == 0) ? qb : (z == 1) ? kb : (Wt + 2 * DM2);
  const int M0 = (z == 2) ? bx * 128 : by * 128;
  const int N0 = (z == 2) ? by * 128 : bx * 128;
  GEMM_BODY(A, Bm, M0, N0)

  if (z == 2) {
    // V: row = token (grb+j), col = feature; V image [dk][key ^ swz(dk)]
    float bv4[4];
#pragma unroll
    for (int n = 0; n < 4; n++) bv4[n] = bv[n0 + wc * 64 + n * 16 + lr];
#pragma unroll
    for (int m = 0; m < 4; m++) {
      const int grb = m0 + wr * 64 + m * 16 + lg * 4;
#pragma unroll
      for (int n = 0; n < 4; n++) {
        const int gc = n0 + wc * 64 + n * 16 + lr;
        const int hh = gc >> 6, dk = gc & 63;
        const int bb = grb >> 11, ss = grb & 2047;
        bf4_t pk;
#pragma unroll
        for (int j = 0; j < 4; j++) pk[j] = (__bf16)(acc[m][n][j] + bv4[n]);
        const int swz = ((dk & 7) * 8) ^ (((dk >> 3) & 3) * 16);
        const size_t addr = (((size_t)bb * NH + hh) * SEQ) * 64 +
                            (size_t)(ss >> 6) * 4096 + dk * 64 +
                            ((ss & 63) ^ swz);
        *(short4v*)&Vb[addr] = __builtin_bit_cast(short4v, pk);
      }
    }
  } else {
    // Q/K swapped: row = feature f (j spans 4 aligned dk), col = token
    const float* bias = (z == 0) ? bq : bk;
    ushort* out = (z == 0) ? Qp : Kp;
    const float scale = (z == 0) ? SCALE_LOG2E : 1.f;
#pragma unroll
    for (int m = 0; m < 4; m++) {
      const int f0 = m0 + wr * 64 + m * 16 + lg * 4;  // aligned 4, one head
      const f32x4 b4 = *(const f32x4*)&bias[f0];
      const int hh = f0 >> 6, dk0 = f0 & 63;
#pragma unroll
      for (int n = 0; n < 4; n++) {
        const int t = n0 + wc * 64 + n * 16 + lr;
        const int b = t >> 11, s = t & 2047;
        bf4_t pk;
#pragma unroll
        for (int j = 0; j < 4; j++)
          pk[j] = (__bf16)((acc[m][n][j] + b4[j]) * scale);
        size_t addr;
        if (z == 0) {
          addr = (((size_t)b * NH + hh) * SEQ + s) * 64 + dk0;
        } else {
          // K image: key*64 + (dk ^ swz(key)); swz mult of 8 keeps 4-runs
          const int swz = ((s & 7) * 8) ^ (((s >> 3) & 3) * 16);
          addr = (((size_t)b * NH + hh) * SEQ) * 64 + (size_t)(s >> 6) * 4096 +
                 (s & 63) * 64 + (dk0 ^ swz);
        }
        *(short4v*)&out[addr] = __builtin_bit_cast(short4v, pk);
      }
    }
  }
}

// Final output GEMM: fp32 row-major epilogue.
__global__ __launch_bounds__(256) void gemmo_k(
    const ushort* __restrict__ Ain, const ushort* __restrict__ Btin,
    const float* __restrict__ bias, float* __restrict__ out) {
  GEMM_BODY(Ain, Btin, blockIdx.x * 128, blockIdx.y * 128)
  float bv4[4];
#pragma unroll
  for (int n = 0; n < 4; n++) bv4[n] = bias[n0 + wc * 64 + n * 16 + lr];
#pragma unroll
  for (int m = 0; m < 4; m++) {
    const int grb = m0 + wr * 64 + m * 16 + lg * 4;
#pragma unroll
    for (int n = 0; n < 4; n++) {
      const int gc = n0 + wc * 64 + n * 16 + lr;
#pragma unroll
      for (int j = 0; j < 4; j++)
        out[(size_t)(grb + j) * DMODEL + gc] = acc[m][n][j] + bv4[n];
    }
  }
}

// ---------------- flash attention, 32x32 MFMA (r13 structure, r17 LDS map) -----
// Zero-pad LDS (32KB -> 5 blocks/CU); bank-free via 2-term image XOR swizzle.
__global__ __launch_bounds__(256) void attn_k(
    const ushort* __restrict__ Qp, const ushort* __restrict__ Kp,
    const ushort* __restrict__ Vt, const float* __restrict__ biasf,
    const unsigned* __restrict__ flags, ushort* __restrict__ ctx) {
  __shared__ ushort smem[4 * TSPAN];  // K dbuf | V dbuf = 32768B; reused for O
  const int tid = threadIdx.x, w = tid >> 6, lane = tid & 63;
  const int q = lane & 31, hi = lane >> 5;
  const int n = blockIdx.x;
  const int xcd = n & 7, idx = n >> 3;
  const int bh = ((idx >> 4) << 3) | xcd;  // 16 consecutive q-tiles share an XCD
  const int qt = idx & 15;
  const int b = bh >> 4, h = bh & 15;
  const int q0w = qt * 128 + w * 32;
  const ushort* Qh = Qp + (size_t)bh * SEQ * 64;
  const ushort* Kh = Kp + (size_t)bh * SEQ * 64;
  const ushort* Vh = Vt + (size_t)bh * SEQ * 64;
  const float* biasb = biasf + b * SEQ;
  const unsigned* flb = flags + b * 32;

  // Q fragments (B-operand of QK^T): col=q, k = c*16 + hi*8 + j
  short8 qf[4];
#pragma unroll
  for (int c = 0; c < 4; c++)
    qf[c] = *(const short8*)&Qh[(size_t)(q0w + q) * 64 + c * 16 + hi * 8];

  // loop-invariant LDS read offsets (shorts); row r at r*64, col ^ swz(r)
  const int xo = ((q & 7) * 8) ^ (((q >> 3) & 3) * 16);
  const int rbase = q * 64;
  int off[4];
#pragma unroll
  for (int c = 0; c < 4; c++) off[c] = rbase + ((c * 16 + hi * 8) ^ xo);

  // staging: wave w covers chunks {2w, 2w+1} (8 rows = 1KB each) of K and V
  const int sl = lane * 8;
  const int c0 = 2 * w, c1 = 2 * w + 1;

  f32x16 o0, o1;
#pragma unroll
  for (int r = 0; r < 16; r++) { o0[r] = 0.f; o1[r] = 0.f; }
  float l_run = 0.f;

  // prologue: stage tile 0 into buffer 0 (async, drained by the barrier)
  gl_lds16(&Kh[c0 * 512 + sl], &smem[c0 * CSTRIDE]);
  gl_lds16(&Kh[c1 * 512 + sl], &smem[c1 * CSTRIDE]);
  gl_lds16(&Vh[c0 * 512 + sl], &smem[2 * TSPAN + c0 * CSTRIDE]);
  gl_lds16(&Vh[c1 * 512 + sl], &smem[2 * TSPAN + c1 * CSTRIDE]);
  __syncthreads();

  for (int it = 0; it < 32; ++it) {
    const int cur = it & 1;
    // stage next tile into the buffer freed by the previous barrier
    if (it < 31) {
      const size_t tb = (size_t)(it + 1) * 4096;
      ushort* kd = &smem[(cur ^ 1) * TSPAN];
      ushort* vd = &smem[2 * TSPAN + (cur ^ 1) * TSPAN];
      gl_lds16(&Kh[tb + c0 * 512 + sl], &kd[c0 * CSTRIDE]);
      gl_lds16(&Kh[tb + c1 * 512 + sl], &kd[c1 * CSTRIDE]);
      gl_lds16(&Vh[tb + c0 * 512 + sl], &vd[c0 * CSTRIDE]);
      gl_lds16(&Vh[tb + c1 * 512 + sl], &vd[c1 * CSTRIDE]);
    }

    const ushort* kl = &smem[cur * TSPAN];
    const ushort* vl = &smem[2 * TSPAN + cur * TSPAN];

    f32x16 s0, s1;
#pragma unroll
    for (int r = 0; r < 16; r++) { s0[r] = 0.f; s1[r] = 0.f; }
#pragma unroll
    for (int c = 0; c < 4; c++)
      s0 = mfma3232(*(const short8*)&kl[off[c]], qf[c], s0);
#pragma unroll
    for (int c = 0; c < 4; c++)
      s1 = mfma3232(*(const short8*)&kl[off[c] + 2048], qf[c], s1);

    // softmax numerator (log2 domain, no shift; masked -> exp2(-1e30)=0)
    float p[32];
    if (flb[it]) {  // uniform branch: tile has masked keys
      const float* bp = biasb + it * 64;
#pragma unroll
      for (int kt = 0; kt < 2; kt++)
#pragma unroll
        for (int g = 0; g < 4; g++) {
          const f32x4 ba = *(const f32x4*)&bp[kt * 32 + g * 8 + hi * 4];
#pragma unroll
          for (int j = 0; j < 4; j++)
            p[kt * 16 + g * 4 + j] =
                fexp2((kt ? s1[g * 4 + j] : s0[g * 4 + j]) + ba[j]);
        }
    } else {
#pragma unroll
      for (int r = 0; r < 16; r++) {
        p[r] = fexp2(s0[r]);
        p[16 + r] = fexp2(s1[r]);
      }
    }

    // tree sum (depth 5)
    float a16[16], a8[8], a4[4];
#pragma unroll
    for (int i = 0; i < 16; i++) a16[i] = p[i] + p[16 + i];
#pragma unroll
    for (int i = 0; i < 8; i++) a8[i] = a16[i] + a16[8 + i];
#pragma unroll
    for (int i = 0; i < 4; i++) a4[i] = a8[i] + a8[4 + i];
    float ps = (a4[0] + a4[1]) + (a4[2] + a4[3]);
    ps += __shfl_xor(ps, 32);
    l_run += ps;

    // P -> PV B-operands: per 16-key block kb, pack 4 u32 then one
    // permlane32_swap per pair fills both B words (lane halves exchanged)
    short8 frag[4];
#pragma unroll
    for (int kb = 0; kb < 4; kb++) {
      unsigned X0 = pk2(p[8 * kb + 0], p[8 * kb + 1]);
      unsigned X1 = pk2(p[8 * kb + 2], p[8 * kb + 3]);
      unsigned Y0 = pk2(p[8 * kb + 4], p[8 * kb + 5]);
      unsigned Y1 = pk2(p[8 * kb + 6], p[8 * kb + 7]);
      plswap(X0, Y0);
      plswap(X1, Y1);
      frag[kb] = __builtin_bit_cast(short8, (uint4v){X0, X1, Y0, Y1});
    }

#pragma unroll
    for (int kb = 0; kb < 4; kb++) {
      o0 = mfma3232(*(const short8*)&vl[off[kb]], frag[kb], o0);
      o1 = mfma3232(*(const short8*)&vl[off[kb] + 2048], frag[kb], o1);
    }

    __syncthreads();  // drains staging loads + this tile's LDS reads
  }

  // epilogue: normalize, bf16 transpose O^T -> row-major via LDS, store
  const float inv = 1.f / l_run;
  ushort* ow = &smem[w * 2176];  // [32 q][68] bf16
#pragma unroll
  for (int r = 0; r < 16; r++) {
    const int dk = (r & 3) + 8 * (r >> 2) + 4 * hi;
    ow[q * 68 + dk] = __builtin_bit_cast(ushort, (__bf16)(o0[r] * inv));
    ow[q * 68 + 32 + dk] = __builtin_bit_cast(ushort, (__bf16)(o1[r] * inv));
  }
  __syncthreads();
  const int sr = lane >> 4, dc = (lane & 15) * 4;
#pragma unroll
  for (int i = 0; i < 8; i++) {
    const int qq = i * 4 + sr;
    const short4v vv = *(const short4v*)&ow[qq * 68 + dc];
    *(short4v*)&ctx[((size_t)b * SEQ + q0w + qq) * DMODEL + h * 64 + dc] = vv;
  }
}

// ---------------- host ---------------------------------------------------------
extern "C" void kernel_launch(void* const* d_in, const int* in_sizes, int n_in,
                              void* d_out, int out_size, void* d_ws,
                              size_t ws_size, hipStream_t stream) {
  const float* q    = (const float*)d_in[0];
  const float* k    = (const float*)d_in[1];
  const float* v    = (const float*)d_in[2];
  const int*   mask = (const int*)d_in[3];
  const float* Wq   = (const float*)d_in[4];
  const float* bq   = (const float*)d_in[5];
  const float* Wk   = (const float*)d_in[6];
  const float* bk   = (const float*)d_in[7];
  const float* Wv   = (const float*)d_in[8];
  const float* bv   = (const float*)d_in[9];
  const float* Wo   = (const float*)d_in[10];
  const float* bo   = (const float*)d_in[11];

  char* p = (char*)d_ws;
  ushort* Wt = (ushort*)p; p += (size_t)4 * DM2 * 2;
  ushort* Qp = (ushort*)p; p += (size_t)MTOT * DMODEL * 2;
  ushort* Kp = (ushort*)p; p += (size_t)MTOT * DMODEL * 2;
  ushort* Vb = (ushort*)p; p += (size_t)MTOT * DMODEL * 2;
  ushort* qb = (ushort*)p; p += (size_t)MTOT * DMODEL * 2;
  ushort* kb = (ushort*)p; p += (size_t)MTOT * DMODEL * 2;
  ushort* vb = (ushort*)p; p += (size_t)MTOT * DMODEL * 2;
  float*  biasf = (float*)p; p += (size_t)NB * SEQ * 4;
  unsigned* flags = (unsigned*)p;
  // ctx aliases qb: qb's last read (Q projection) precedes attn on the stream
  ushort* ctx = qb;

  wtrans_k<<<dim3(32, 32, 4), dim3(32, 32), 0, stream>>>(Wq, Wk, Wv, Wo, Wt);
  cvt3_k<<<dim3(MTOT * DMODEL / (256 * 8), 3), 256, 0, stream>>>(
      q, k, v, qb, kb, vb, mask, biasf, flags);

  gemmqkv_k<<<dim3(MTOT / 128, DMODEL / 128, 3), 256, 0, stream>>>(
      qb, kb, vb, Wt, bq, bk, bv, Qp, Kp, Vb);

  attn_k<<<1024, 256, 0, stream>>>(Qp, Kp, Vb, biasf, flags, ctx);

  gemmo_k<<<dim3(MTOT / 128, DMODEL / 128), 256, 0, stream>>>(
      ctx, Wt + (size_t)3 * DM2, bo, (float*)d_out);
}